// Round 1
// baseline (277.694 us; speedup 1.0000x reference)
//
#include <hip/hip_runtime.h>

#define NBINS 256
#define NCH 3
#define HSIZE (NBINS * NCH)   // 768
#define NWAVE 4               // waves per block (256 threads)
#define SLOTS 16              // global partial-histogram copies
#define TPB 256
#define BLOCKS 2048

// Process one float4 whose first element has channel base giving offsets o0,o1,o2
// (channels within a float4 cycle m, m+1, m+2, m since 4 == 1 mod 3).
#define PROC(v, o0, o1, o2)                                          \
    do {                                                             \
        int b0 = (int)((v).x * 256.0f); b0 = min(max(b0, 0), 255);   \
        int b1 = (int)((v).y * 256.0f); b1 = min(max(b1, 0), 255);   \
        int b2 = (int)((v).z * 256.0f); b2 = min(max(b2, 0), 255);   \
        int b3 = (int)((v).w * 256.0f); b3 = min(max(b3, 0), 255);   \
        atomicAdd(&h[(o0) + b0], 1u);                                \
        atomicAdd(&h[(o1) + b1], 1u);                                \
        atomicAdd(&h[(o2) + b2], 1u);                                \
        atomicAdd(&h[(o0) + b3], 1u);                                \
    } while (0)

__global__ __launch_bounds__(TPB) void hist_kernel(const float* __restrict__ in,
                                                   unsigned int* __restrict__ ws,
                                                   int n) {
    __shared__ unsigned int lds[NWAVE][HSIZE];

    const int tid = threadIdx.x;
    const int wave = tid >> 6;

    // zero LDS (3072 words / 256 threads = 12 each)
    unsigned int* flat = &lds[0][0];
    #pragma unroll
    for (int i = 0; i < NWAVE * HSIZE / TPB; ++i)
        flat[tid + i * TPB] = 0u;
    __syncthreads();

    unsigned int* h = lds[wave];

    const int n4 = n >> 2;                             // float4 count
    const long long gtid = (long long)blockIdx.x * TPB + tid;
    const long long S    = (long long)gridDim.x * TPB; // stride in float4s
    const float4* __restrict__ in4 = (const float4*)in;

    // channel of first element of float4 i: (4*i) % 3 == i % 3  (4 ≡ 1 mod 3)
    const int m0 = (int)(gtid % 3);
    const int ms = (int)(S % 3);
    // After 3 strided iterations the channel rotation is 3*ms ≡ 0 (mod 3):
    // channel pattern is invariant across unroll-3 groups. Hoist all offsets.
    int mA = m0;
    int mB = mA + ms; if (mB >= 3) mB -= 3;
    int mC = mB + ms; if (mC >= 3) mC -= 3;

    const int oA0 = mA * NBINS;
    const int oA1 = ((mA + 1 >= 3) ? mA - 2 : mA + 1) * NBINS;
    const int oA2 = ((mA + 2 >= 3) ? mA - 1 : mA + 2) * NBINS;
    const int oB0 = mB * NBINS;
    const int oB1 = ((mB + 1 >= 3) ? mB - 2 : mB + 1) * NBINS;
    const int oB2 = ((mB + 2 >= 3) ? mB - 1 : mB + 2) * NBINS;
    const int oC0 = mC * NBINS;
    const int oC1 = ((mC + 1 >= 3) ? mC - 2 : mC + 1) * NBINS;
    const int oC2 = ((mC + 2 >= 3) ? mC - 1 : mC + 2) * NBINS;

    long long i = gtid;
    // Main loop: 6 independent float4 loads in flight (6x memory-level parallelism).
    for (; i + 5 * S < n4; i += 6 * S) {
        float4 v0 = in4[i];
        float4 v1 = in4[i + S];
        float4 v2 = in4[i + 2 * S];
        float4 v3 = in4[i + 3 * S];
        float4 v4 = in4[i + 4 * S];
        float4 v5 = in4[i + 5 * S];
        PROC(v0, oA0, oA1, oA2);
        PROC(v1, oB0, oB1, oB2);
        PROC(v2, oC0, oC1, oC2);
        PROC(v3, oA0, oA1, oA2);
        PROC(v4, oB0, oB1, oB2);
        PROC(v5, oC0, oC1, oC2);
    }
    // Leftover strided iterations (≤5); channel pattern repeats with period 3.
    if (i < n4) { float4 v = in4[i]; PROC(v, oA0, oA1, oA2); i += S; }
    if (i < n4) { float4 v = in4[i]; PROC(v, oB0, oB1, oB2); i += S; }
    if (i < n4) { float4 v = in4[i]; PROC(v, oC0, oC1, oC2); i += S; }
    if (i < n4) { float4 v = in4[i]; PROC(v, oA0, oA1, oA2); i += S; }
    if (i < n4) { float4 v = in4[i]; PROC(v, oB0, oB1, oB2); i += S; }

    // scalar tail (n not divisible by 4) — only block 0
    if (blockIdx.x == 0) {
        for (int e = (n4 << 2) + tid; e < n; e += TPB) {
            float x = in[e];
            int b = (int)(x * 256.0f); b = min(max(b, 0), 255);
            int c = e % 3;
            atomicAdd(&h[c * NBINS + b], 1u);
        }
    }

    __syncthreads();

    // flush: sum the 4 wave copies, one global atomic per bin per block
    unsigned int* dst = ws + (blockIdx.x & (SLOTS - 1)) * HSIZE;
    #pragma unroll
    for (int i2 = 0; i2 < HSIZE / TPB; ++i2) {
        int idx = tid + i2 * TPB;
        unsigned int s = lds[0][idx] + lds[1][idx] + lds[2][idx] + lds[3][idx];
        if (s) atomicAdd(&dst[idx], s);
    }
}

__global__ void finalize_kernel(const unsigned int* __restrict__ ws,
                                float* __restrict__ out,
                                float total) {
    int t = threadIdx.x;          // 0..767
    int bin = t / 3;
    int c = t - 3 * bin;
    unsigned int s = 0;
    #pragma unroll
    for (int k = 0; k < SLOTS; ++k)
        s += ws[k * HSIZE + c * NBINS + bin];
    out[t] = (float)s / total;    // out layout: [bin, channel]
}

extern "C" void kernel_launch(void* const* d_in, const int* in_sizes, int n_in,
                              void* d_out, int out_size, void* d_ws, size_t ws_size,
                              hipStream_t stream) {
    const float* in = (const float*)d_in[0];
    const int n = in_sizes[0];
    unsigned int* ws = (unsigned int*)d_ws;

    hipMemsetAsync(ws, 0, SLOTS * HSIZE * sizeof(unsigned int), stream);
    hist_kernel<<<BLOCKS, TPB, 0, stream>>>(in, ws, n);
    finalize_kernel<<<1, HSIZE, 0, stream>>>(ws, (float*)d_out, (float)(n / NCH));
}